// Round 14
// baseline (468.905 us; speedup 1.0000x reference)
//
#include <hip/hip_runtime.h>
#include <cstddef>
#include <cstdint>

// Problem constants (match reference)
constexpr int CB  = 2;     // batch
constexpr int CS  = 2048;  // seq len
constexpr int CDM = 1024;  // d_model
constexpr int CH  = 16;    // heads
constexpr int CHD = 64;    // head dim
constexpr int CTPF = 128;  // tokens per frame
constexpr int CNF = 16;    // frames

typedef __attribute__((ext_vector_type(8))) short short8;
typedef __attribute__((ext_vector_type(4))) float f32x4;

__device__ inline ushort f32_bf16_rne(float x) {
  uint32_t u = __float_as_uint(x);
  u += 0x7FFFu + ((u >> 16) & 1u);
  return (ushort)(u >> 16);
}
__device__ inline float bf16_f32(ushort h) {
  return __uint_as_float(((uint32_t)h) << 16);
}
// split 8 floats into hi/lo bf16 vectors
__device__ inline void split8(const float* v, short8& H, short8& L) {
#pragma unroll
  for (int j = 0; j < 8; ++j) {
    const ushort hh = f32_bf16_rne(v[j]);
    H[j] = (short)hh;
    L[j] = (short)f32_bf16_rne(v[j] - bf16_f32(hh));
  }
}

// ---------------------------------------------------------------------------
// split_pass: fp32 -> bf16 hi/lo, memory-bound grid-stride.
// ---------------------------------------------------------------------------
__global__ __launch_bounds__(256) void split_pass(
    const float* __restrict__ src, ushort* __restrict__ h,
    ushort* __restrict__ l, int n8) {
  int i = blockIdx.x * 256 + threadIdx.x;
  const int stride = gridDim.x * 256;
  for (; i < n8; i += stride) {
    float v[8];
    *(float4*)&v[0] = ((const float4*)src)[2 * i];
    *(float4*)&v[4] = ((const float4*)src)[2 * i + 1];
    short8 H, L;
    split8(v, H, L);
    *(short8*)&h[(size_t)i * 8] = H;
    *(short8*)&l[(size_t)i * 8] = L;
  }
}

// ---------------------------------------------------------------------------
// gemm_fused_qkv: qkv GEMM with the ENTIRE qkv_prep fused into the epilogue.
// Main loop identical to the validated gemm_ps v2 (global_load_lds width=16,
// pre-swizzled global source, conflict-free). Epilogue exploits that a
// wave's 64x64 sub-tile = 64 rows x exactly ONE head:
//   region Q (bn<8):  RMSNorm (in-lane 4-sum + shfl_xor 1/2/4/8 over the
//                     16-lane row group) + RoPE (partner d^32 = nf^2, same
//                     lane) + 0.125 scale + h/l split -> Qh/Ql
//   region K (8..15): same minus 0.125 -> Kh/Kl
//   region V (>=16):  transpose via 16.9KB LDS tile (4 passes: head-half x
//                     h/l) -> Vth/Vtl [B,H,64,S]
// Eliminates the qkv fp32 intermediate (50MB W + 50MB R) and the prep kernel.
// LDS 48.9 KB -> 3 blocks/CU.
// ---------------------------------------------------------------------------
__global__ __launch_bounds__(256) void gemm_fused_qkv(
    const ushort* __restrict__ Ah, const ushort* __restrict__ Al,
    const ushort* __restrict__ Bh, const ushort* __restrict__ Bl,
    const float* __restrict__ bias, const float* __restrict__ q_scale,
    const float* __restrict__ k_scale,
    ushort* __restrict__ Qh, ushort* __restrict__ Ql,
    ushort* __restrict__ Kh, ushort* __restrict__ Kl,
    ushort* __restrict__ Vth, ushort* __restrict__ Vtl) {
  __shared__ ushort As_h[128 * 32], As_l[128 * 32];
  __shared__ ushort Bs_h[128 * 32], Bs_l[128 * 32];
  __shared__ ushort VT[64 * 132];  // V-transpose staging (epilogue only)
  const int K = CDM;               // 1024
  const int tid = threadIdx.x;
  const int bnr = blockIdx.x;      // 0..23
  const int bm = blockIdx.y * 128;
  const int bn = bnr * 128;
  const int wid = tid >> 6;
  const int lane = tid & 63;
  const int wm = wid >> 1;
  const int wn = wid & 1;
  const int l15 = lane & 15;
  const int lk = lane >> 4;
  const int srow = tid >> 2;
  const int kq = (tid & 3) * 8;

  f32x4 acc[4][4];
#pragma unroll
  for (int i = 0; i < 4; ++i)
#pragma unroll
    for (int j = 0; j < 4; ++j) acc[i][j] = (f32x4){0.f, 0.f, 0.f, 0.f};

  for (int k0 = 0; k0 < K; k0 += 32) {
    __syncthreads();
#pragma unroll
    for (int c = 0; c < 2; ++c) {
      const int row = srow + c * 64;
      const int kg = kq ^ ((row & 6) << 2);  // pre-swizzled global col
      const size_t ga = (size_t)(bm + row) * K + k0 + kg;
      const size_t gb = (size_t)(bn + row) * K + k0 + kg;
      const int lo = tid * 8 + c * 2048;
      __builtin_amdgcn_global_load_lds(
          (const __attribute__((address_space(1))) void*)(Ah + ga),
          (__attribute__((address_space(3))) void*)&As_h[lo], 16, 0, 0);
      __builtin_amdgcn_global_load_lds(
          (const __attribute__((address_space(1))) void*)(Al + ga),
          (__attribute__((address_space(3))) void*)&As_l[lo], 16, 0, 0);
      __builtin_amdgcn_global_load_lds(
          (const __attribute__((address_space(1))) void*)(Bh + gb),
          (__attribute__((address_space(3))) void*)&Bs_h[lo], 16, 0, 0);
      __builtin_amdgcn_global_load_lds(
          (const __attribute__((address_space(1))) void*)(Bl + gb),
          (__attribute__((address_space(3))) void*)&Bs_l[lo], 16, 0, 0);
    }
    __syncthreads();

    short8 ah[4], al[4], bh[4], bl[4];
#pragma unroll
    for (int fI = 0; fI < 4; ++fI) {
      const int ar = wm * 64 + fI * 16 + l15;
      const int aoff = ar * 32 + ((lk * 8) ^ ((ar & 6) << 2));
      ah[fI] = *(const short8*)&As_h[aoff];
      al[fI] = *(const short8*)&As_l[aoff];
      const int br = wn * 64 + fI * 16 + l15;
      const int boff = br * 32 + ((lk * 8) ^ ((br & 6) << 2));
      bh[fI] = *(const short8*)&Bs_h[boff];
      bl[fI] = *(const short8*)&Bs_l[boff];
    }
#pragma unroll
    for (int mf = 0; mf < 4; ++mf)
#pragma unroll
      for (int nf = 0; nf < 4; ++nf) {
        acc[mf][nf] = __builtin_amdgcn_mfma_f32_16x16x32_bf16(
            ah[mf], bh[nf], acc[mf][nf], 0, 0, 0);
        acc[mf][nf] = __builtin_amdgcn_mfma_f32_16x16x32_bf16(
            ah[mf], bl[nf], acc[mf][nf], 0, 0, 0);
        acc[mf][nf] = __builtin_amdgcn_mfma_f32_16x16x32_bf16(
            al[mf], bh[nf], acc[mf][nf], 0, 0, 0);
      }
  }

  // bias (bqkv) into acc
#pragma unroll
  for (int nf = 0; nf < 4; ++nf) {
    const float bc = bias[bn + wn * 64 + nf * 16 + l15];
#pragma unroll
    for (int mf = 0; mf < 4; ++mf)
#pragma unroll
      for (int i = 0; i < 4; ++i) acc[mf][nf][i] += bc;
  }

  const int region = bnr >> 3;  // 0=Q, 1=K, 2=V
  const int bloc = bm >> 11;    // batch (tile never straddles: 128 | 2048)
  const int sbase = bm & (CS - 1);

  if (region < 2) {
    const float* scale = (region == 0) ? q_scale : k_scale;
    ushort* Dh = (region == 0) ? Qh : Kh;
    ushort* Dl = (region == 0) ? Ql : Kl;
    const float qmul = (region == 0) ? 0.125f : 1.0f;
    const int hh = (bnr - region * 8) * 2 + wn;  // wave's head
    const size_t hbout = ((size_t)(bloc * CH + hh)) * CS;
    float sc[4];
#pragma unroll
    for (int nf = 0; nf < 4; ++nf) sc[nf] = scale[nf * 16 + l15];
    const float inv0 = powf(10000.0f, -(float)l15 * (1.0f / 32.0f));
    const float inv1 = powf(10000.0f, -(float)(16 + l15) * (1.0f / 32.0f));
#pragma unroll
    for (int mf = 0; mf < 4; ++mf)
#pragma unroll
      for (int i = 0; i < 4; ++i) {
        const int stok = sbase + wm * 64 + mf * 16 + lk * 4 + i;
        // RMSNorm: sum of squares over the 64 dims of this row
        float ss = 0.f;
#pragma unroll
        for (int nf = 0; nf < 4; ++nf)
          ss = fmaf(acc[mf][nf][i], acc[mf][nf][i], ss);
        ss += __shfl_xor(ss, 1);
        ss += __shfl_xor(ss, 2);
        ss += __shfl_xor(ss, 4);
        ss += __shfl_xor(ss, 8);
        const float rms = rsqrtf(ss * (1.0f / 64.0f) + 1e-6f);
        const float v0 = acc[mf][0][i] * rms * sc[0];
        const float v1 = acc[mf][1][i] * rms * sc[1];
        const float v2 = acc[mf][2][i] * rms * sc[2];
        const float v3 = acc[mf][3][i] * rms * sc[3];
        // RoPE: d = nf*16+l15; j = d&31 (nf even -> l15, odd -> 16+l15);
        // partner = d^32 = nf^2 (same lane); sign - for d<32, + for d>=32.
        const float a0 = (float)stok * inv0;
        const float a1 = (float)stok * inv1;
        const float c0 = cosf(a0), s0 = sinf(a0);
        const float c1 = cosf(a1), s1 = sinf(a1);
        const float o0 = (v0 * c0 - v2 * s0) * qmul;
        const float o1 = (v1 * c1 - v3 * s1) * qmul;
        const float o2 = (v2 * c0 + v0 * s0) * qmul;
        const float o3 = (v3 * c1 + v1 * s1) * qmul;
        const size_t ob = (hbout + stok) * CHD + l15;
        ushort t;
        t = f32_bf16_rne(o0); Dh[ob] = t;
        Dl[ob] = f32_bf16_rne(o0 - bf16_f32(t));
        t = f32_bf16_rne(o1); Dh[ob + 16] = t;
        Dl[ob + 16] = f32_bf16_rne(o1 - bf16_f32(t));
        t = f32_bf16_rne(o2); Dh[ob + 32] = t;
        Dl[ob + 32] = f32_bf16_rne(o2 - bf16_f32(t));
        t = f32_bf16_rne(o3); Dh[ob + 48] = t;
        Dl[ob + 48] = f32_bf16_rne(o3 - bf16_f32(t));
      }
  } else {
    // V: transpose to Vt[B,H,64,S] via LDS; 4 passes (head-half p x h/l)
    const int p0 = bnr - 16;
#pragma unroll 1
    for (int p = 0; p < 2; ++p) {
#pragma unroll 1
      for (int ph = 0; ph < 2; ++ph) {
        __syncthreads();  // VT free (prev pass readers / staging done)
        if (wn == p) {
#pragma unroll
          for (int mf = 0; mf < 4; ++mf)
#pragma unroll
            for (int nf = 0; nf < 4; ++nf)
#pragma unroll
              for (int i = 0; i < 4; ++i) {
                const float v = acc[mf][nf][i];
                const ushort hv = f32_bf16_rne(v);
                const ushort u =
                    (ph == 0) ? hv : f32_bf16_rne(v - bf16_f32(hv));
                VT[(nf * 16 + l15) * 132 + wm * 64 + mf * 16 + lk * 4 + i] = u;
              }
        }
        __syncthreads();
        // coalesced write-out: 256 thr cover 64 d-rows x 128 s
        const int cl = tid >> 2;         // d 0..63
        const int seg = (tid & 3) * 32;  // s segment
        const int head = p0 * 2 + p;
        ushort* dst = ((ph == 0) ? Vth : Vtl) +
            (((size_t)(bloc * CH + head)) * CHD + cl) * CS + sbase + seg;
        const ushort* srcp = &VT[cl * 132 + seg];
#pragma unroll
        for (int k2 = 0; k2 < 4; ++k2)
          *(short8*)(dst + k2 * 8) = *(const short8*)(srcp + k2 * 8);
      }
    }
  }
}

// ---------------------------------------------------------------------------
// gemm_ps (validated R13): used for the output projection.
// ---------------------------------------------------------------------------
__global__ __launch_bounds__(256) void gemm_ps(
    const ushort* __restrict__ Ah, const ushort* __restrict__ Al,
    const ushort* __restrict__ Bh, const ushort* __restrict__ Bl,
    const float* __restrict__ bias, float* __restrict__ C,
    int M, int N, int K) {
  __shared__ ushort As_h[128 * 32], As_l[128 * 32];
  __shared__ ushort Bs_h[128 * 32], Bs_l[128 * 32];
  const int tid = threadIdx.x;
  const int bm = blockIdx.y * 128;
  const int bn = blockIdx.x * 128;
  const int wid = tid >> 6;
  const int lane = tid & 63;
  const int wm = wid >> 1;
  const int wn = wid & 1;
  const int l15 = lane & 15;
  const int lk = lane >> 4;
  const int srow = tid >> 2;
  const int kq = (tid & 3) * 8;

  f32x4 acc[4][4];
#pragma unroll
  for (int i = 0; i < 4; ++i)
#pragma unroll
    for (int j = 0; j < 4; ++j) acc[i][j] = (f32x4){0.f, 0.f, 0.f, 0.f};

  for (int k0 = 0; k0 < K; k0 += 32) {
    __syncthreads();
#pragma unroll
    for (int c = 0; c < 2; ++c) {
      const int row = srow + c * 64;
      const int kg = kq ^ ((row & 6) << 2);
      const size_t ga = (size_t)(bm + row) * K + k0 + kg;
      const size_t gb = (size_t)(bn + row) * K + k0 + kg;
      const int lo = tid * 8 + c * 2048;
      __builtin_amdgcn_global_load_lds(
          (const __attribute__((address_space(1))) void*)(Ah + ga),
          (__attribute__((address_space(3))) void*)&As_h[lo], 16, 0, 0);
      __builtin_amdgcn_global_load_lds(
          (const __attribute__((address_space(1))) void*)(Al + ga),
          (__attribute__((address_space(3))) void*)&As_l[lo], 16, 0, 0);
      __builtin_amdgcn_global_load_lds(
          (const __attribute__((address_space(1))) void*)(Bh + gb),
          (__attribute__((address_space(3))) void*)&Bs_h[lo], 16, 0, 0);
      __builtin_amdgcn_global_load_lds(
          (const __attribute__((address_space(1))) void*)(Bl + gb),
          (__attribute__((address_space(3))) void*)&Bs_l[lo], 16, 0, 0);
    }
    __syncthreads();

    short8 ah[4], al[4], bh[4], bl[4];
#pragma unroll
    for (int fI = 0; fI < 4; ++fI) {
      const int ar = wm * 64 + fI * 16 + l15;
      const int aoff = ar * 32 + ((lk * 8) ^ ((ar & 6) << 2));
      ah[fI] = *(const short8*)&As_h[aoff];
      al[fI] = *(const short8*)&As_l[aoff];
      const int br = wn * 64 + fI * 16 + l15;
      const int boff = br * 32 + ((lk * 8) ^ ((br & 6) << 2));
      bh[fI] = *(const short8*)&Bs_h[boff];
      bl[fI] = *(const short8*)&Bs_l[boff];
    }
#pragma unroll
    for (int mf = 0; mf < 4; ++mf)
#pragma unroll
      for (int nf = 0; nf < 4; ++nf) {
        acc[mf][nf] = __builtin_amdgcn_mfma_f32_16x16x32_bf16(
            ah[mf], bh[nf], acc[mf][nf], 0, 0, 0);
        acc[mf][nf] = __builtin_amdgcn_mfma_f32_16x16x32_bf16(
            ah[mf], bl[nf], acc[mf][nf], 0, 0, 0);
        acc[mf][nf] = __builtin_amdgcn_mfma_f32_16x16x32_bf16(
            al[mf], bh[nf], acc[mf][nf], 0, 0, 0);
      }
  }

#pragma unroll
  for (int mf = 0; mf < 4; ++mf)
#pragma unroll
    for (int nf = 0; nf < 4; ++nf) {
      const int col = bn + wn * 64 + nf * 16 + l15;
      const int row0 = bm + wm * 64 + mf * 16 + lk * 4;
      const float bc = bias[col];
#pragma unroll
      for (int i = 0; i < 4; ++i)
        C[(size_t)(row0 + i) * N + col] = acc[mf][nf][i] + bc;
    }
}

// ---------------------------------------------------------------------------
// attn_fwd_mfma (validated R12/R13): swapped QK^T, XOR-swizzled LDS, 3-term
// split, balanced frame pairing, pre-split O output.
// ---------------------------------------------------------------------------
__global__ __launch_bounds__(256, 2) void attn_fwd_mfma(
    const ushort* __restrict__ Qh, const ushort* __restrict__ Ql,
    const ushort* __restrict__ Kh, const ushort* __restrict__ Kl,
    const ushort* __restrict__ Vth, const ushort* __restrict__ Vtl,
    ushort* __restrict__ Oh, ushort* __restrict__ Ol) {
  __shared__ ushort Ks_h[64 * 64], Ks_l[64 * 64];   // K chunk [key][d]
  __shared__ ushort Vs_h[64 * 64], Vs_l[64 * 64];   // V^T chunk [d][key]
  __shared__ ushort Ps_h[128 * 64], Ps_l[128 * 64]; // P [q][key], wave-priv
  const int tid = threadIdx.x;
  const int b = blockIdx.x;
  const int h = blockIdx.y;
  const int fsel = blockIdx.z;
  const int f = (fsel < 8) ? (15 - fsel) : (fsel - 8);  // balanced pairing
  const int lane = tid & 63;
  const int wid = tid >> 6;
  const int l15 = lane & 15;
  const int lk = lane >> 4;
  const int qb = wid * 32;
  const size_t hb = ((size_t)(b * CH + h)) * CS * CHD;
  const size_t vtb = ((size_t)(b * CH + h)) * CHD * CS;

  short8 qh[2][2], ql[2][2];
#pragma unroll
  for (int nf = 0; nf < 2; ++nf)
#pragma unroll
    for (int ks = 0; ks < 2; ++ks) {
      const size_t qoff = hb +
          (size_t)(f * CTPF + qb + nf * 16 + l15) * CHD + ks * 32 + lk * 8;
      qh[nf][ks] = *(const short8*)(Qh + qoff);
      ql[nf][ks] = *(const short8*)(Ql + qoff);
    }

  f32x4 accO[2][4];
#pragma unroll
  for (int mo = 0; mo < 2; ++mo)
#pragma unroll
    for (int no = 0; no < 4; ++no) accO[mo][no] = (f32x4){0.f, 0.f, 0.f, 0.f};
  float m[2] = {-1e30f, -1e30f};
  float lsum[2] = {0.f, 0.f};

  const int kf0 = (f == CNF - 1) ? 1 : 0;  // last-frame quirk
  for (int kf = kf0; kf <= f; ++kf) {
#pragma unroll 1
    for (int half = 0; half < 2; ++half) {
      const int cb = kf * CTPF + half * 64;
      __syncthreads();
      {
        const int r = tid >> 2;
        const int cq = (tid & 3) * 16;
        const int mk = (r & 7) << 3;
        const size_t ko = hb + (size_t)(cb + r) * CHD + cq;
        *(short8*)&Ks_h[r * 64 + (cq ^ mk)] = *(const short8*)(Kh + ko);
        *(short8*)&Ks_h[r * 64 + ((cq + 8) ^ mk)] = *(const short8*)(Kh + ko + 8);
        *(short8*)&Ks_l[r * 64 + (cq ^ mk)] = *(const short8*)(Kl + ko);
        *(short8*)&Ks_l[r * 64 + ((cq + 8) ^ mk)] = *(const short8*)(Kl + ko + 8);
        const size_t vo = vtb + (size_t)r * CS + cb + cq;
        *(short8*)&Vs_h[r * 64 + (cq ^ mk)] = *(const short8*)(Vth + vo);
        *(short8*)&Vs_h[r * 64 + ((cq + 8) ^ mk)] = *(const short8*)(Vth + vo + 8);
        *(short8*)&Vs_l[r * 64 + (cq ^ mk)] = *(const short8*)(Vtl + vo);
        *(short8*)&Vs_l[r * 64 + ((cq + 8) ^ mk)] = *(const short8*)(Vtl + vo + 8);
      }
      __syncthreads();

      f32x4 sacc[4][2];
#pragma unroll
      for (int mf = 0; mf < 4; ++mf)
#pragma unroll
        for (int nf = 0; nf < 2; ++nf) sacc[mf][nf] = (f32x4){0.f, 0.f, 0.f, 0.f};
#pragma unroll
      for (int ks = 0; ks < 2; ++ks) {
        short8 kh[4], kl[4];
#pragma unroll
        for (int mf = 0; mf < 4; ++mf) {
          const int krow = mf * 16 + l15;
          const int base = krow * 64 + ((ks * 32 + lk * 8) ^ ((krow & 7) << 3));
          kh[mf] = *(const short8*)&Ks_h[base];
          kl[mf] = *(const short8*)&Ks_l[base];
        }
#pragma unroll
        for (int mf = 0; mf < 4; ++mf)
#pragma unroll
          for (int nf = 0; nf < 2; ++nf) {
            sacc[mf][nf] = __builtin_amdgcn_mfma_f32_16x16x32_bf16(
                kh[mf], qh[nf][ks], sacc[mf][nf], 0, 0, 0);
            sacc[mf][nf] = __builtin_amdgcn_mfma_f32_16x16x32_bf16(
                kh[mf], ql[nf][ks], sacc[mf][nf], 0, 0, 0);
            sacc[mf][nf] = __builtin_amdgcn_mfma_f32_16x16x32_bf16(
                kl[mf], qh[nf][ks], sacc[mf][nf], 0, 0, 0);
          }
      }

      float c[2];
#pragma unroll
      for (int nf = 0; nf < 2; ++nf) {
        float cm = sacc[0][nf][0];
#pragma unroll
        for (int mf = 0; mf < 4; ++mf)
#pragma unroll
          for (int i = 0; i < 4; ++i) cm = fmaxf(cm, sacc[mf][nf][i]);
        cm = fmaxf(cm, __shfl_xor(cm, 16));
        cm = fmaxf(cm, __shfl_xor(cm, 32));
        const float mn = fmaxf(m[nf], cm);
        c[nf] = __expf(m[nf] - mn);
        m[nf] = mn;
        float ps = 0.f;
        const int qrow = qb + nf * 16 + l15;
        const int qmk = (qrow & 7) << 3;
#pragma unroll
        for (int mf = 0; mf < 4; ++mf) {
          float p0 = __expf(sacc[mf][nf][0] - mn);
          float p1 = __expf(sacc[mf][nf][1] - mn);
          float p2 = __expf(sacc[mf][nf][2] - mn);
          float p3 = __expf(sacc[mf][nf][3] - mn);
          ps += (p0 + p1) + (p2 + p3);
          const ushort h0 = f32_bf16_rne(p0), h1 = f32_bf16_rne(p1);
          const ushort h2 = f32_bf16_rne(p2), h3 = f32_bf16_rne(p3);
          uint2 hw, lw;
          hw.x = (uint32_t)h0 | ((uint32_t)h1 << 16);
          hw.y = (uint32_t)h2 | ((uint32_t)h3 << 16);
          lw.x = (uint32_t)f32_bf16_rne(p0 - bf16_f32(h0)) |
                 ((uint32_t)f32_bf16_rne(p1 - bf16_f32(h1)) << 16);
          lw.y = (uint32_t)f32_bf16_rne(p2 - bf16_f32(h2)) |
                 ((uint32_t)f32_bf16_rne(p3 - bf16_f32(h3)) << 16);
          const int off = qrow * 64 + ((mf * 16 + lk * 4) ^ qmk);
          *(uint2*)&Ps_h[off] = hw;
          *(uint2*)&Ps_l[off] = lw;
        }
        ps += __shfl_xor(ps, 16);
        ps += __shfl_xor(ps, 32);
        lsum[nf] = lsum[nf] * c[nf] + ps;
      }
#pragma unroll
      for (int mo = 0; mo < 2; ++mo)
#pragma unroll
        for (int i = 0; i < 4; ++i) {
          const float cq = __shfl(c[mo], lk * 4 + i);
#pragma unroll
          for (int no = 0; no < 4; ++no) accO[mo][no][i] *= cq;
        }

#pragma unroll
      for (int ks = 0; ks < 2; ++ks) {
        short8 pa_h[2], pa_l[2], vb_h[4], vb_l[4];
#pragma unroll
        for (int mo = 0; mo < 2; ++mo) {
          const int qrow = qb + mo * 16 + l15;
          const int base = qrow * 64 + ((ks * 32 + lk * 8) ^ ((qrow & 7) << 3));
          pa_h[mo] = *(const short8*)&Ps_h[base];
          pa_l[mo] = *(const short8*)&Ps_l[base];
        }
#pragma unroll
        for (int no = 0; no < 4; ++no) {
          const int vrow = no * 16 + l15;
          const int base = vrow * 64 + ((ks * 32 + lk * 8) ^ ((vrow & 7) << 3));
          vb_h[no] = *(const short8*)&Vs_h[base];
          vb_l[no] = *(const short8*)&Vs_l[base];
        }
#pragma unroll
        for (int mo = 0; mo < 2; ++mo)
#pragma unroll
          for (int no = 0; no < 4; ++no) {
            accO[mo][no] = __builtin_amdgcn_mfma_f32_16x16x32_bf16(
                pa_h[mo], vb_h[no], accO[mo][no], 0, 0, 0);
            accO[mo][no] = __builtin_amdgcn_mfma_f32_16x16x32_bf16(
                pa_h[mo], vb_l[no], accO[mo][no], 0, 0, 0);
            accO[mo][no] = __builtin_amdgcn_mfma_f32_16x16x32_bf16(
                pa_l[mo], vb_h[no], accO[mo][no], 0, 0, 0);
          }
      }
    }
  }

  const float il0 = 1.f / lsum[0];
  const float il1 = 1.f / lsum[1];
#pragma unroll
  for (int mo = 0; mo < 2; ++mo) {
    const float myil = (mo == 0) ? il0 : il1;
#pragma unroll
    for (int i = 0; i < 4; ++i) {
      const float wv = __shfl(myil, lk * 4 + i);
      const int srow = f * CTPF + qb + mo * 16 + lk * 4 + i;
      const size_t obase = (size_t)(b * CS + srow) * CDM + h * CHD;
#pragma unroll
      for (int no = 0; no < 4; ++no) {
        const float val = accO[mo][no][i] * wv;
        const ushort hh = f32_bf16_rne(val);
        Oh[obase + no * 16 + l15] = hh;
        Ol[obase + no * 16 + l15] = f32_bf16_rne(val - bf16_f32(hh));
      }
    }
  }
}

// ---------------------------------------------------------------------------
extern "C" void kernel_launch(void* const* d_in, const int* in_sizes, int n_in,
                              void* d_out, int out_size, void* d_ws, size_t ws_size,
                              hipStream_t stream) {
  const float* x       = (const float*)d_in[0];
  const float* Wqkv    = (const float*)d_in[1];
  const float* bqkv    = (const float*)d_in[2];
  const float* q_scale = (const float*)d_in[3];
  const float* k_scale = (const float*)d_in[4];
  const float* Wout    = (const float*)d_in[5];
  const float* bout    = (const float*)d_in[6];
  float* out = (float*)d_out;

  // Workspace (ushort units), 84 MB total:
  //  [0,6P):   Qh Ql Kh Kl Vth Vtl   (written by GEMM1 epilogue, read by attn)
  //  [6P,8P):  xh xl  (live split..GEMM1)  -> aliased as Oh Ol (attn..GEMM2)
  //  then Wqh Wql (split..GEMM1), Wouth Woutl (split..GEMM2)
  ushort* W = (ushort*)d_ws;
  const size_t perA = (size_t)CB * CH * CS * CHD;      // 4.19M elems
  const size_t WqN  = (size_t)(3 * CDM) * CDM;         // 3.15M
  const size_t WoN  = (size_t)CDM * CDM;               // 1.05M

  ushort* Qh  = W;
  ushort* Ql  = W + perA;
  ushort* Kh  = W + 2 * perA;
  ushort* Kl  = W + 3 * perA;
  ushort* Vth = W + 4 * perA;
  ushort* Vtl = W + 5 * perA;
  ushort* xh  = W + 6 * perA;
  ushort* xl  = W + 7 * perA;
  ushort* Oh  = xh;  // dead after GEMM1
  ushort* Ol  = xl;
  ushort* Wqh = W + 8 * perA;
  ushort* Wql = Wqh + WqN;
  ushort* Wouth = Wql + WqN;
  ushort* Woutl = Wouth + WoN;

  // 0) one-time fp32 -> bf16 h/l splits (memory-bound)
  split_pass<<<2048, 256, 0, stream>>>(x, xh, xl, (int)(perA / 8));
  split_pass<<<1536, 256, 0, stream>>>(Wqkv, Wqh, Wql, (int)(WqN / 8));
  split_pass<<<512, 256, 0, stream>>>(Wout, Wouth, Woutl, (int)(WoN / 8));

  // 1) fused: qkv GEMM + RMSNorm + RoPE + split + V-transpose
  dim3 g1((3 * CDM) / 128, (CB * CS) / 128);
  gemm_fused_qkv<<<g1, 256, 0, stream>>>(xh, xl, Wqh, Wql, bqkv,
                                         q_scale, k_scale,
                                         Qh, Ql, Kh, Kl, Vth, Vtl);

  // 2) frame-block-causal attention on MFMA -> pre-split O
  dim3 g3(CB, CH, CNF);
  attn_fwd_mfma<<<g3, 256, 0, stream>>>(Qh, Ql, Kh, Kl, Vth, Vtl, Oh, Ol);

  // 3) out = O @ Wout^T + bout
  dim3 g4(CDM / 128, (CB * CS) / 128);
  gemm_ps<<<g4, 256, 0, stream>>>(Oh, Ol, Wouth, Woutl, bout, out,
                                  CB * CS, CDM, CDM);
}

// Round 15
// 468.207 us; speedup vs baseline: 1.0015x; 1.0015x over previous
//
#include <hip/hip_runtime.h>
#include <cstddef>
#include <cstdint>

// Problem constants (match reference)
constexpr int CB  = 2;     // batch
constexpr int CS  = 2048;  // seq len
constexpr int CDM = 1024;  // d_model
constexpr int CH  = 16;    // heads
constexpr int CHD = 64;    // head dim
constexpr int CTPF = 128;  // tokens per frame
constexpr int CNF = 16;    // frames

typedef __attribute__((ext_vector_type(8))) short short8;
typedef __attribute__((ext_vector_type(4))) float f32x4;

__device__ inline ushort f32_bf16_rne(float x) {
  uint32_t u = __float_as_uint(x);
  u += 0x7FFFu + ((u >> 16) & 1u);
  return (ushort)(u >> 16);
}
__device__ inline float bf16_f32(ushort h) {
  return __uint_as_float(((uint32_t)h) << 16);
}
// split 8 floats into hi/lo bf16 vectors
__device__ inline void split8(const float* v, short8& H, short8& L) {
#pragma unroll
  for (int j = 0; j < 8; ++j) {
    const ushort hh = f32_bf16_rne(v[j]);
    H[j] = (short)hh;
    L[j] = (short)f32_bf16_rne(v[j] - bf16_f32(hh));
  }
}

// ---------------------------------------------------------------------------
// split_pass: fp32 -> bf16 hi/lo, memory-bound grid-stride.
// ---------------------------------------------------------------------------
__global__ __launch_bounds__(256) void split_pass(
    const float* __restrict__ src, ushort* __restrict__ h,
    ushort* __restrict__ l, int n8) {
  int i = blockIdx.x * 256 + threadIdx.x;
  const int stride = gridDim.x * 256;
  for (; i < n8; i += stride) {
    float v[8];
    *(float4*)&v[0] = ((const float4*)src)[2 * i];
    *(float4*)&v[4] = ((const float4*)src)[2 * i + 1];
    short8 H, L;
    split8(v, H, L);
    *(short8*)&h[(size_t)i * 8] = H;
    *(short8*)&l[(size_t)i * 8] = L;
  }
}

// ---------------------------------------------------------------------------
// gemm_fused_qkv v2: qkv GEMM + RMSNorm + RoPE + split + V-transpose.
// R14 diagnosis: Q/K epilogue scalar 2B stores scattered (lane owns dims
// {l15,+16,+32,+48}) -> 4x32B partial-line segments/inst -> 1.03 GB HBM
// write amplification, kernel write-bound at 350us.
// FIX: Q/K stored in d-PERMUTED layout pi(d) = (d&15)*4 + (d>>4), so a
// thread's 4 dims are CONTIGUOUS (addr token*64 + l15*4 + 0..3) -> one 8B
// uint2 store per array; 16-lane group = 128B fully coalesced.
// Correctness: QK^T is a dot over d; attention reads Q (reg frags) and K
// (LDS frags) with the IDENTICAL addr formula, so permuting both operands'
// k-slots consistently leaves the dot invariant (same argument as R7's
// k-slot cancellation). No other consumer interprets Q/K's d-index.
// ---------------------------------------------------------------------------
__global__ __launch_bounds__(256) void gemm_fused_qkv(
    const ushort* __restrict__ Ah, const ushort* __restrict__ Al,
    const ushort* __restrict__ Bh, const ushort* __restrict__ Bl,
    const float* __restrict__ bias, const float* __restrict__ q_scale,
    const float* __restrict__ k_scale,
    ushort* __restrict__ Qh, ushort* __restrict__ Ql,
    ushort* __restrict__ Kh, ushort* __restrict__ Kl,
    ushort* __restrict__ Vth, ushort* __restrict__ Vtl) {
  __shared__ ushort As_h[128 * 32], As_l[128 * 32];
  __shared__ ushort Bs_h[128 * 32], Bs_l[128 * 32];
  __shared__ ushort VT[64 * 132];  // V-transpose staging (epilogue only)
  const int K = CDM;               // 1024
  const int tid = threadIdx.x;
  const int bnr = blockIdx.x;      // 0..23
  const int bm = blockIdx.y * 128;
  const int bn = bnr * 128;
  const int wid = tid >> 6;
  const int lane = tid & 63;
  const int wm = wid >> 1;
  const int wn = wid & 1;
  const int l15 = lane & 15;
  const int lk = lane >> 4;
  const int srow = tid >> 2;
  const int kq = (tid & 3) * 8;

  f32x4 acc[4][4];
#pragma unroll
  for (int i = 0; i < 4; ++i)
#pragma unroll
    for (int j = 0; j < 4; ++j) acc[i][j] = (f32x4){0.f, 0.f, 0.f, 0.f};

  for (int k0 = 0; k0 < K; k0 += 32) {
    __syncthreads();
#pragma unroll
    for (int c = 0; c < 2; ++c) {
      const int row = srow + c * 64;
      const int kg = kq ^ ((row & 6) << 2);  // pre-swizzled global col
      const size_t ga = (size_t)(bm + row) * K + k0 + kg;
      const size_t gb = (size_t)(bn + row) * K + k0 + kg;
      const int lo = tid * 8 + c * 2048;
      __builtin_amdgcn_global_load_lds(
          (const __attribute__((address_space(1))) void*)(Ah + ga),
          (__attribute__((address_space(3))) void*)&As_h[lo], 16, 0, 0);
      __builtin_amdgcn_global_load_lds(
          (const __attribute__((address_space(1))) void*)(Al + ga),
          (__attribute__((address_space(3))) void*)&As_l[lo], 16, 0, 0);
      __builtin_amdgcn_global_load_lds(
          (const __attribute__((address_space(1))) void*)(Bh + gb),
          (__attribute__((address_space(3))) void*)&Bs_h[lo], 16, 0, 0);
      __builtin_amdgcn_global_load_lds(
          (const __attribute__((address_space(1))) void*)(Bl + gb),
          (__attribute__((address_space(3))) void*)&Bs_l[lo], 16, 0, 0);
    }
    __syncthreads();

    short8 ah[4], al[4], bh[4], bl[4];
#pragma unroll
    for (int fI = 0; fI < 4; ++fI) {
      const int ar = wm * 64 + fI * 16 + l15;
      const int aoff = ar * 32 + ((lk * 8) ^ ((ar & 6) << 2));
      ah[fI] = *(const short8*)&As_h[aoff];
      al[fI] = *(const short8*)&As_l[aoff];
      const int br = wn * 64 + fI * 16 + l15;
      const int boff = br * 32 + ((lk * 8) ^ ((br & 6) << 2));
      bh[fI] = *(const short8*)&Bs_h[boff];
      bl[fI] = *(const short8*)&Bs_l[boff];
    }
#pragma unroll
    for (int mf = 0; mf < 4; ++mf)
#pragma unroll
      for (int nf = 0; nf < 4; ++nf) {
        acc[mf][nf] = __builtin_amdgcn_mfma_f32_16x16x32_bf16(
            ah[mf], bh[nf], acc[mf][nf], 0, 0, 0);
        acc[mf][nf] = __builtin_amdgcn_mfma_f32_16x16x32_bf16(
            ah[mf], bl[nf], acc[mf][nf], 0, 0, 0);
        acc[mf][nf] = __builtin_amdgcn_mfma_f32_16x16x32_bf16(
            al[mf], bh[nf], acc[mf][nf], 0, 0, 0);
      }
  }

  // bias (bqkv) into acc
#pragma unroll
  for (int nf = 0; nf < 4; ++nf) {
    const float bc = bias[bn + wn * 64 + nf * 16 + l15];
#pragma unroll
    for (int mf = 0; mf < 4; ++mf)
#pragma unroll
      for (int i = 0; i < 4; ++i) acc[mf][nf][i] += bc;
  }

  const int region = bnr >> 3;  // 0=Q, 1=K, 2=V
  const int bloc = bm >> 11;    // batch (tile never straddles: 128 | 2048)
  const int sbase = bm & (CS - 1);

  if (region < 2) {
    const float* scale = (region == 0) ? q_scale : k_scale;
    ushort* Dh = (region == 0) ? Qh : Kh;
    ushort* Dl = (region == 0) ? Ql : Kl;
    const float qmul = (region == 0) ? 0.125f : 1.0f;
    const int hh = (bnr - region * 8) * 2 + wn;  // wave's head
    const size_t hbout = ((size_t)(bloc * CH + hh)) * CS;
    float sc[4];
#pragma unroll
    for (int nf = 0; nf < 4; ++nf) sc[nf] = scale[nf * 16 + l15];
    const float inv0 = powf(10000.0f, -(float)l15 * (1.0f / 32.0f));
    const float inv1 = powf(10000.0f, -(float)(16 + l15) * (1.0f / 32.0f));
#pragma unroll
    for (int mf = 0; mf < 4; ++mf)
#pragma unroll
      for (int i = 0; i < 4; ++i) {
        const int stok = sbase + wm * 64 + mf * 16 + lk * 4 + i;
        // RMSNorm: sum of squares over the 64 dims of this row
        float ss = 0.f;
#pragma unroll
        for (int nf = 0; nf < 4; ++nf)
          ss = fmaf(acc[mf][nf][i], acc[mf][nf][i], ss);
        ss += __shfl_xor(ss, 1);
        ss += __shfl_xor(ss, 2);
        ss += __shfl_xor(ss, 4);
        ss += __shfl_xor(ss, 8);
        const float rms = rsqrtf(ss * (1.0f / 64.0f) + 1e-6f);
        const float v0 = acc[mf][0][i] * rms * sc[0];
        const float v1 = acc[mf][1][i] * rms * sc[1];
        const float v2 = acc[mf][2][i] * rms * sc[2];
        const float v3 = acc[mf][3][i] * rms * sc[3];
        // RoPE: d = nf*16+l15; partner d^32 = nf^2 (same lane).
        const float a0 = (float)stok * inv0;
        const float a1 = (float)stok * inv1;
        const float c0 = cosf(a0), s0 = sinf(a0);
        const float c1 = cosf(a1), s1 = sinf(a1);
        const float o0 = (v0 * c0 - v2 * s0) * qmul;
        const float o1 = (v1 * c1 - v3 * s1) * qmul;
        const float o2 = (v2 * c0 + v0 * s0) * qmul;
        const float o3 = (v3 * c1 + v1 * s1) * qmul;
        // permuted-d store: pi(nf*16+l15) = l15*4 + nf -> uint2 (8B) per
        // array; 16-lane group = 128B contiguous (fixes R14's 1GB write amp)
        const ushort h0 = f32_bf16_rne(o0), h1 = f32_bf16_rne(o1);
        const ushort h2 = f32_bf16_rne(o2), h3 = f32_bf16_rne(o3);
        uint2 hw, lw;
        hw.x = (uint32_t)h0 | ((uint32_t)h1 << 16);
        hw.y = (uint32_t)h2 | ((uint32_t)h3 << 16);
        lw.x = (uint32_t)f32_bf16_rne(o0 - bf16_f32(h0)) |
               ((uint32_t)f32_bf16_rne(o1 - bf16_f32(h1)) << 16);
        lw.y = (uint32_t)f32_bf16_rne(o2 - bf16_f32(h2)) |
               ((uint32_t)f32_bf16_rne(o3 - bf16_f32(h3)) << 16);
        const size_t ob = (hbout + stok) * CHD + l15 * 4;
        *(uint2*)(Dh + ob) = hw;
        *(uint2*)(Dl + ob) = lw;
      }
  } else {
    // V: transpose to Vt[B,H,64,S] via LDS; 4 passes (head-half p x h/l)
    const int p0 = bnr - 16;
#pragma unroll 1
    for (int p = 0; p < 2; ++p) {
#pragma unroll 1
      for (int ph = 0; ph < 2; ++ph) {
        __syncthreads();  // VT free (prev pass readers / staging done)
        if (wn == p) {
#pragma unroll
          for (int mf = 0; mf < 4; ++mf)
#pragma unroll
            for (int nf = 0; nf < 4; ++nf)
#pragma unroll
              for (int i = 0; i < 4; ++i) {
                const float v = acc[mf][nf][i];
                const ushort hv = f32_bf16_rne(v);
                const ushort u =
                    (ph == 0) ? hv : f32_bf16_rne(v - bf16_f32(hv));
                VT[(nf * 16 + l15) * 132 + wm * 64 + mf * 16 + lk * 4 + i] = u;
              }
        }
        __syncthreads();
        // coalesced write-out: 256 thr cover 64 d-rows x 128 s
        const int cl = tid >> 2;         // d 0..63
        const int seg = (tid & 3) * 32;  // s segment
        const int head = p0 * 2 + p;
        ushort* dst = ((ph == 0) ? Vth : Vtl) +
            (((size_t)(bloc * CH + head)) * CHD + cl) * CS + sbase + seg;
        const ushort* srcp = &VT[cl * 132 + seg];
#pragma unroll
        for (int k2 = 0; k2 < 4; ++k2)
          *(short8*)(dst + k2 * 8) = *(const short8*)(srcp + k2 * 8);
      }
    }
  }
}

// ---------------------------------------------------------------------------
// gemm_ps (validated R13): used for the output projection.
// ---------------------------------------------------------------------------
__global__ __launch_bounds__(256) void gemm_ps(
    const ushort* __restrict__ Ah, const ushort* __restrict__ Al,
    const ushort* __restrict__ Bh, const ushort* __restrict__ Bl,
    const float* __restrict__ bias, float* __restrict__ C,
    int M, int N, int K) {
  __shared__ ushort As_h[128 * 32], As_l[128 * 32];
  __shared__ ushort Bs_h[128 * 32], Bs_l[128 * 32];
  const int tid = threadIdx.x;
  const int bm = blockIdx.y * 128;
  const int bn = blockIdx.x * 128;
  const int wid = tid >> 6;
  const int lane = tid & 63;
  const int wm = wid >> 1;
  const int wn = wid & 1;
  const int l15 = lane & 15;
  const int lk = lane >> 4;
  const int srow = tid >> 2;
  const int kq = (tid & 3) * 8;

  f32x4 acc[4][4];
#pragma unroll
  for (int i = 0; i < 4; ++i)
#pragma unroll
    for (int j = 0; j < 4; ++j) acc[i][j] = (f32x4){0.f, 0.f, 0.f, 0.f};

  for (int k0 = 0; k0 < K; k0 += 32) {
    __syncthreads();
#pragma unroll
    for (int c = 0; c < 2; ++c) {
      const int row = srow + c * 64;
      const int kg = kq ^ ((row & 6) << 2);
      const size_t ga = (size_t)(bm + row) * K + k0 + kg;
      const size_t gb = (size_t)(bn + row) * K + k0 + kg;
      const int lo = tid * 8 + c * 2048;
      __builtin_amdgcn_global_load_lds(
          (const __attribute__((address_space(1))) void*)(Ah + ga),
          (__attribute__((address_space(3))) void*)&As_h[lo], 16, 0, 0);
      __builtin_amdgcn_global_load_lds(
          (const __attribute__((address_space(1))) void*)(Al + ga),
          (__attribute__((address_space(3))) void*)&As_l[lo], 16, 0, 0);
      __builtin_amdgcn_global_load_lds(
          (const __attribute__((address_space(1))) void*)(Bh + gb),
          (__attribute__((address_space(3))) void*)&Bs_h[lo], 16, 0, 0);
      __builtin_amdgcn_global_load_lds(
          (const __attribute__((address_space(1))) void*)(Bl + gb),
          (__attribute__((address_space(3))) void*)&Bs_l[lo], 16, 0, 0);
    }
    __syncthreads();

    short8 ah[4], al[4], bh[4], bl[4];
#pragma unroll
    for (int fI = 0; fI < 4; ++fI) {
      const int ar = wm * 64 + fI * 16 + l15;
      const int aoff = ar * 32 + ((lk * 8) ^ ((ar & 6) << 2));
      ah[fI] = *(const short8*)&As_h[aoff];
      al[fI] = *(const short8*)&As_l[aoff];
      const int br = wn * 64 + fI * 16 + l15;
      const int boff = br * 32 + ((lk * 8) ^ ((br & 6) << 2));
      bh[fI] = *(const short8*)&Bs_h[boff];
      bl[fI] = *(const short8*)&Bs_l[boff];
    }
#pragma unroll
    for (int mf = 0; mf < 4; ++mf)
#pragma unroll
      for (int nf = 0; nf < 4; ++nf) {
        acc[mf][nf] = __builtin_amdgcn_mfma_f32_16x16x32_bf16(
            ah[mf], bh[nf], acc[mf][nf], 0, 0, 0);
        acc[mf][nf] = __builtin_amdgcn_mfma_f32_16x16x32_bf16(
            ah[mf], bl[nf], acc[mf][nf], 0, 0, 0);
        acc[mf][nf] = __builtin_amdgcn_mfma_f32_16x16x32_bf16(
            al[mf], bh[nf], acc[mf][nf], 0, 0, 0);
      }
  }

#pragma unroll
  for (int mf = 0; mf < 4; ++mf)
#pragma unroll
    for (int nf = 0; nf < 4; ++nf) {
      const int col = bn + wn * 64 + nf * 16 + l15;
      const int row0 = bm + wm * 64 + mf * 16 + lk * 4;
      const float bc = bias[col];
#pragma unroll
      for (int i = 0; i < 4; ++i)
        C[(size_t)(row0 + i) * N + col] = acc[mf][nf][i] + bc;
    }
}

// ---------------------------------------------------------------------------
// attn_fwd_mfma (validated R12/R13): swapped QK^T, XOR-swizzled LDS, 3-term
// split, balanced frame pairing, pre-split O output. Q/K arrive d-permuted
// (pi(d) = (d&15)*4 + (d>>4)); both operands permuted identically, so QK^T
// is unchanged. V/Vt unpermuted.
// ---------------------------------------------------------------------------
__global__ __launch_bounds__(256, 2) void attn_fwd_mfma(
    const ushort* __restrict__ Qh, const ushort* __restrict__ Ql,
    const ushort* __restrict__ Kh, const ushort* __restrict__ Kl,
    const ushort* __restrict__ Vth, const ushort* __restrict__ Vtl,
    ushort* __restrict__ Oh, ushort* __restrict__ Ol) {
  __shared__ ushort Ks_h[64 * 64], Ks_l[64 * 64];   // K chunk [key][d]
  __shared__ ushort Vs_h[64 * 64], Vs_l[64 * 64];   // V^T chunk [d][key]
  __shared__ ushort Ps_h[128 * 64], Ps_l[128 * 64]; // P [q][key], wave-priv
  const int tid = threadIdx.x;
  const int b = blockIdx.x;
  const int h = blockIdx.y;
  const int fsel = blockIdx.z;
  const int f = (fsel < 8) ? (15 - fsel) : (fsel - 8);  // balanced pairing
  const int lane = tid & 63;
  const int wid = tid >> 6;
  const int l15 = lane & 15;
  const int lk = lane >> 4;
  const int qb = wid * 32;
  const size_t hb = ((size_t)(b * CH + h)) * CS * CHD;
  const size_t vtb = ((size_t)(b * CH + h)) * CHD * CS;

  short8 qh[2][2], ql[2][2];
#pragma unroll
  for (int nf = 0; nf < 2; ++nf)
#pragma unroll
    for (int ks = 0; ks < 2; ++ks) {
      const size_t qoff = hb +
          (size_t)(f * CTPF + qb + nf * 16 + l15) * CHD + ks * 32 + lk * 8;
      qh[nf][ks] = *(const short8*)(Qh + qoff);
      ql[nf][ks] = *(const short8*)(Ql + qoff);
    }

  f32x4 accO[2][4];
#pragma unroll
  for (int mo = 0; mo < 2; ++mo)
#pragma unroll
    for (int no = 0; no < 4; ++no) accO[mo][no] = (f32x4){0.f, 0.f, 0.f, 0.f};
  float m[2] = {-1e30f, -1e30f};
  float lsum[2] = {0.f, 0.f};

  const int kf0 = (f == CNF - 1) ? 1 : 0;  // last-frame quirk
  for (int kf = kf0; kf <= f; ++kf) {
#pragma unroll 1
    for (int half = 0; half < 2; ++half) {
      const int cb = kf * CTPF + half * 64;
      __syncthreads();
      {
        const int r = tid >> 2;
        const int cq = (tid & 3) * 16;
        const int mk = (r & 7) << 3;
        const size_t ko = hb + (size_t)(cb + r) * CHD + cq;
        *(short8*)&Ks_h[r * 64 + (cq ^ mk)] = *(const short8*)(Kh + ko);
        *(short8*)&Ks_h[r * 64 + ((cq + 8) ^ mk)] = *(const short8*)(Kh + ko + 8);
        *(short8*)&Ks_l[r * 64 + (cq ^ mk)] = *(const short8*)(Kl + ko);
        *(short8*)&Ks_l[r * 64 + ((cq + 8) ^ mk)] = *(const short8*)(Kl + ko + 8);
        const size_t vo = vtb + (size_t)r * CS + cb + cq;
        *(short8*)&Vs_h[r * 64 + (cq ^ mk)] = *(const short8*)(Vth + vo);
        *(short8*)&Vs_h[r * 64 + ((cq + 8) ^ mk)] = *(const short8*)(Vth + vo + 8);
        *(short8*)&Vs_l[r * 64 + (cq ^ mk)] = *(const short8*)(Vtl + vo);
        *(short8*)&Vs_l[r * 64 + ((cq + 8) ^ mk)] = *(const short8*)(Vtl + vo + 8);
      }
      __syncthreads();

      f32x4 sacc[4][2];
#pragma unroll
      for (int mf = 0; mf < 4; ++mf)
#pragma unroll
        for (int nf = 0; nf < 2; ++nf) sacc[mf][nf] = (f32x4){0.f, 0.f, 0.f, 0.f};
#pragma unroll
      for (int ks = 0; ks < 2; ++ks) {
        short8 kh[4], kl[4];
#pragma unroll
        for (int mf = 0; mf < 4; ++mf) {
          const int krow = mf * 16 + l15;
          const int base = krow * 64 + ((ks * 32 + lk * 8) ^ ((krow & 7) << 3));
          kh[mf] = *(const short8*)&Ks_h[base];
          kl[mf] = *(const short8*)&Ks_l[base];
        }
#pragma unroll
        for (int mf = 0; mf < 4; ++mf)
#pragma unroll
          for (int nf = 0; nf < 2; ++nf) {
            sacc[mf][nf] = __builtin_amdgcn_mfma_f32_16x16x32_bf16(
                kh[mf], qh[nf][ks], sacc[mf][nf], 0, 0, 0);
            sacc[mf][nf] = __builtin_amdgcn_mfma_f32_16x16x32_bf16(
                kh[mf], ql[nf][ks], sacc[mf][nf], 0, 0, 0);
            sacc[mf][nf] = __builtin_amdgcn_mfma_f32_16x16x32_bf16(
                kl[mf], qh[nf][ks], sacc[mf][nf], 0, 0, 0);
          }
      }

      float c[2];
#pragma unroll
      for (int nf = 0; nf < 2; ++nf) {
        float cm = sacc[0][nf][0];
#pragma unroll
        for (int mf = 0; mf < 4; ++mf)
#pragma unroll
          for (int i = 0; i < 4; ++i) cm = fmaxf(cm, sacc[mf][nf][i]);
        cm = fmaxf(cm, __shfl_xor(cm, 16));
        cm = fmaxf(cm, __shfl_xor(cm, 32));
        const float mn = fmaxf(m[nf], cm);
        c[nf] = __expf(m[nf] - mn);
        m[nf] = mn;
        float ps = 0.f;
        const int qrow = qb + nf * 16 + l15;
        const int qmk = (qrow & 7) << 3;
#pragma unroll
        for (int mf = 0; mf < 4; ++mf) {
          float p0 = __expf(sacc[mf][nf][0] - mn);
          float p1 = __expf(sacc[mf][nf][1] - mn);
          float p2 = __expf(sacc[mf][nf][2] - mn);
          float p3 = __expf(sacc[mf][nf][3] - mn);
          ps += (p0 + p1) + (p2 + p3);
          const ushort h0 = f32_bf16_rne(p0), h1 = f32_bf16_rne(p1);
          const ushort h2 = f32_bf16_rne(p2), h3 = f32_bf16_rne(p3);
          uint2 hw, lw;
          hw.x = (uint32_t)h0 | ((uint32_t)h1 << 16);
          hw.y = (uint32_t)h2 | ((uint32_t)h3 << 16);
          lw.x = (uint32_t)f32_bf16_rne(p0 - bf16_f32(h0)) |
                 ((uint32_t)f32_bf16_rne(p1 - bf16_f32(h1)) << 16);
          lw.y = (uint32_t)f32_bf16_rne(p2 - bf16_f32(h2)) |
                 ((uint32_t)f32_bf16_rne(p3 - bf16_f32(h3)) << 16);
          const int off = qrow * 64 + ((mf * 16 + lk * 4) ^ qmk);
          *(uint2*)&Ps_h[off] = hw;
          *(uint2*)&Ps_l[off] = lw;
        }
        ps += __shfl_xor(ps, 16);
        ps += __shfl_xor(ps, 32);
        lsum[nf] = lsum[nf] * c[nf] + ps;
      }
#pragma unroll
      for (int mo = 0; mo < 2; ++mo)
#pragma unroll
        for (int i = 0; i < 4; ++i) {
          const float cq = __shfl(c[mo], lk * 4 + i);
#pragma unroll
          for (int no = 0; no < 4; ++no) accO[mo][no][i] *= cq;
        }

#pragma unroll
      for (int ks = 0; ks < 2; ++ks) {
        short8 pa_h[2], pa_l[2], vb_h[4], vb_l[4];
#pragma unroll
        for (int mo = 0; mo < 2; ++mo) {
          const int qrow = qb + mo * 16 + l15;
          const int base = qrow * 64 + ((ks * 32 + lk * 8) ^ ((qrow & 7) << 3));
          pa_h[mo] = *(const short8*)&Ps_h[base];
          pa_l[mo] = *(const short8*)&Ps_l[base];
        }
#pragma unroll
        for (int no = 0; no < 4; ++no) {
          const int vrow = no * 16 + l15;
          const int base = vrow * 64 + ((ks * 32 + lk * 8) ^ ((vrow & 7) << 3));
          vb_h[no] = *(const short8*)&Vs_h[base];
          vb_l[no] = *(const short8*)&Vs_l[base];
        }
#pragma unroll
        for (int mo = 0; mo < 2; ++mo)
#pragma unroll
          for (int no = 0; no < 4; ++no) {
            accO[mo][no] = __builtin_amdgcn_mfma_f32_16x16x32_bf16(
                pa_h[mo], vb_h[no], accO[mo][no], 0, 0, 0);
            accO[mo][no] = __builtin_amdgcn_mfma_f32_16x16x32_bf16(
                pa_h[mo], vb_l[no], accO[mo][no], 0, 0, 0);
            accO[mo][no] = __builtin_amdgcn_mfma_f32_16x16x32_bf16(
                pa_l[mo], vb_h[no], accO[mo][no], 0, 0, 0);
          }
      }
    }
  }

  const float il0 = 1.f / lsum[0];
  const float il1 = 1.f / lsum[1];
#pragma unroll
  for (int mo = 0; mo < 2; ++mo) {
    const float myil = (mo == 0) ? il0 : il1;
#pragma unroll
    for (int i = 0; i < 4; ++i) {
      const float wv = __shfl(myil, lk * 4 + i);
      const int srow = f * CTPF + qb + mo * 16 + lk * 4 + i;
      const size_t obase = (size_t)(b * CS + srow) * CDM + h * CHD;
#pragma unroll
      for (int no = 0; no < 4; ++no) {
        const float val = accO[mo][no][i] * wv;
        const ushort hh = f32_bf16_rne(val);
        Oh[obase + no * 16 + l15] = hh;
        Ol[obase + no * 16 + l15] = f32_bf16_rne(val - bf16_f32(hh));
      }
    }
  }
}

// ---------------------------------------------------------------------------
extern "C" void kernel_launch(void* const* d_in, const int* in_sizes, int n_in,
                              void* d_out, int out_size, void* d_ws, size_t ws_size,
                              hipStream_t stream) {
  const float* x       = (const float*)d_in[0];
  const float* Wqkv    = (const float*)d_in[1];
  const float* bqkv    = (const float*)d_in[2];
  const float* q_scale = (const float*)d_in[3];
  const float* k_scale = (const float*)d_in[4];
  const float* Wout    = (const float*)d_in[5];
  const float* bout    = (const float*)d_in[6];
  float* out = (float*)d_out;

  // Workspace (ushort units), 84 MB total:
  //  [0,6P):   Qh Ql Kh Kl Vth Vtl   (written by GEMM1 epilogue, read by attn)
  //  [6P,8P):  xh xl  (live split..GEMM1)  -> aliased as Oh Ol (attn..GEMM2)
  //  then Wqh Wql (split..GEMM1), Wouth Woutl (split..GEMM2)
  ushort* W = (ushort*)d_ws;
  const size_t perA = (size_t)CB * CH * CS * CHD;      // 4.19M elems
  const size_t WqN  = (size_t)(3 * CDM) * CDM;         // 3.15M
  const size_t WoN  = (size_t)CDM * CDM;               // 1.05M

  ushort* Qh  = W;
  ushort* Ql  = W + perA;
  ushort* Kh  = W + 2 * perA;
  ushort* Kl  = W + 3 * perA;
  ushort* Vth = W + 4 * perA;
  ushort* Vtl = W + 5 * perA;
  ushort* xh  = W + 6 * perA;
  ushort* xl  = W + 7 * perA;
  ushort* Oh  = xh;  // dead after GEMM1
  ushort* Ol  = xl;
  ushort* Wqh = W + 8 * perA;
  ushort* Wql = Wqh + WqN;
  ushort* Wouth = Wql + WqN;
  ushort* Woutl = Wouth + WoN;

  // 0) one-time fp32 -> bf16 h/l splits (memory-bound)
  split_pass<<<2048, 256, 0, stream>>>(x, xh, xl, (int)(perA / 8));
  split_pass<<<1536, 256, 0, stream>>>(Wqkv, Wqh, Wql, (int)(WqN / 8));
  split_pass<<<512, 256, 0, stream>>>(Wout, Wouth, Woutl, (int)(WoN / 8));

  // 1) fused: qkv GEMM + RMSNorm + RoPE + split + V-transpose
  dim3 g1((3 * CDM) / 128, (CB * CS) / 128);
  gemm_fused_qkv<<<g1, 256, 0, stream>>>(xh, xl, Wqh, Wql, bqkv,
                                         q_scale, k_scale,
                                         Qh, Ql, Kh, Kl, Vth, Vtl);

  // 2) frame-block-causal attention on MFMA -> pre-split O
  dim3 g3(CB, CH, CNF);
  attn_fwd_mfma<<<g3, 256, 0, stream>>>(Qh, Ql, Kh, Kl, Vth, Vtl, Oh, Ol);

  // 3) out = O @ Wout^T + bout
  dim3 g4(CDM / 128, (CB * CS) / 128);
  gemm_ps<<<g4, 256, 0, stream>>>(Oh, Ol, Wouth, Woutl, bout, out,
                                  CB * CS, CDM, CDM);
}

// Round 16
// 252.252 us; speedup vs baseline: 1.8589x; 1.8561x over previous
//
#include <hip/hip_runtime.h>
#include <cstddef>
#include <cstdint>

// Problem constants (match reference)
constexpr int CB  = 2;     // batch
constexpr int CS  = 2048;  // seq len
constexpr int CDM = 1024;  // d_model
constexpr int CH  = 16;    // heads
constexpr int CHD = 64;    // head dim
constexpr int CTPF = 128;  // tokens per frame
constexpr int CNF = 16;    // frames

typedef __attribute__((ext_vector_type(8))) short short8;
typedef __attribute__((ext_vector_type(4))) float f32x4;

__device__ inline ushort f32_bf16_rne(float x) {
  uint32_t u = __float_as_uint(x);
  u += 0x7FFFu + ((u >> 16) & 1u);
  return (ushort)(u >> 16);
}
__device__ inline float bf16_f32(ushort h) {
  return __uint_as_float(((uint32_t)h) << 16);
}
// split 8 floats into hi/lo bf16 vectors
__device__ inline void split8(const float* v, short8& H, short8& L) {
#pragma unroll
  for (int j = 0; j < 8; ++j) {
    const ushort hh = f32_bf16_rne(v[j]);
    H[j] = (short)hh;
    L[j] = (short)f32_bf16_rne(v[j] - bf16_f32(hh));
  }
}

// ---------------------------------------------------------------------------
// split3: one launch splits x, Wqkv, Wout fp32 -> bf16 h/l (was 3 launches;
// merged to save two launch tails). Pure memory op, grid-stride.
// ---------------------------------------------------------------------------
__global__ __launch_bounds__(256) void split3(
    const float* __restrict__ s0, ushort* __restrict__ h0,
    ushort* __restrict__ l0, int n0,
    const float* __restrict__ s1, ushort* __restrict__ h1,
    ushort* __restrict__ l1, int n1,
    const float* __restrict__ s2, ushort* __restrict__ h2,
    ushort* __restrict__ l2, int n2) {
  const int ntot = n0 + n1 + n2;
  int i = blockIdx.x * 256 + threadIdx.x;
  const int stride = gridDim.x * 256;
  for (; i < ntot; i += stride) {
    const float* src;
    ushort *h, *l;
    int j = i;
    if (j < n0) {
      src = s0; h = h0; l = l0;
    } else if ((j -= n0) < n1) {
      src = s1; h = h1; l = l1;
    } else {
      j -= n1; src = s2; h = h2; l = l2;
    }
    float v[8];
    *(float4*)&v[0] = ((const float4*)src)[2 * j];
    *(float4*)&v[4] = ((const float4*)src)[2 * j + 1];
    short8 H, L;
    split8(v, H, L);
    *(short8*)&h[(size_t)j * 8] = H;
    *(short8*)&l[(size_t)j * 8] = L;
  }
}

// ---------------------------------------------------------------------------
// gemm_ps v2 (validated R13): C[M,N] = A[M,K] @ B[N,K]^T + bias[N],
// pre-split bf16 h/l. global_load_lds width=16, pre-swizzled global source,
// linear LDS dest, conflict-free reads. 32 KB LDS.
// ---------------------------------------------------------------------------
__global__ __launch_bounds__(256) void gemm_ps(
    const ushort* __restrict__ Ah, const ushort* __restrict__ Al,
    const ushort* __restrict__ Bh, const ushort* __restrict__ Bl,
    const float* __restrict__ bias, float* __restrict__ C,
    int M, int N, int K) {
  __shared__ ushort As_h[128 * 32], As_l[128 * 32];
  __shared__ ushort Bs_h[128 * 32], Bs_l[128 * 32];
  const int tid = threadIdx.x;
  const int bm = blockIdx.y * 128;
  const int bn = blockIdx.x * 128;
  const int wid = tid >> 6;
  const int lane = tid & 63;
  const int wm = wid >> 1;
  const int wn = wid & 1;
  const int l15 = lane & 15;
  const int lk = lane >> 4;
  const int srow = tid >> 2;
  const int kq = (tid & 3) * 8;

  f32x4 acc[4][4];
#pragma unroll
  for (int i = 0; i < 4; ++i)
#pragma unroll
    for (int j = 0; j < 4; ++j) acc[i][j] = (f32x4){0.f, 0.f, 0.f, 0.f};

  for (int k0 = 0; k0 < K; k0 += 32) {
    __syncthreads();
#pragma unroll
    for (int c = 0; c < 2; ++c) {
      const int row = srow + c * 64;
      const int kg = kq ^ ((row & 6) << 2);
      const size_t ga = (size_t)(bm + row) * K + k0 + kg;
      const size_t gb = (size_t)(bn + row) * K + k0 + kg;
      const int lo = tid * 8 + c * 2048;
      __builtin_amdgcn_global_load_lds(
          (const __attribute__((address_space(1))) void*)(Ah + ga),
          (__attribute__((address_space(3))) void*)&As_h[lo], 16, 0, 0);
      __builtin_amdgcn_global_load_lds(
          (const __attribute__((address_space(1))) void*)(Al + ga),
          (__attribute__((address_space(3))) void*)&As_l[lo], 16, 0, 0);
      __builtin_amdgcn_global_load_lds(
          (const __attribute__((address_space(1))) void*)(Bh + gb),
          (__attribute__((address_space(3))) void*)&Bs_h[lo], 16, 0, 0);
      __builtin_amdgcn_global_load_lds(
          (const __attribute__((address_space(1))) void*)(Bl + gb),
          (__attribute__((address_space(3))) void*)&Bs_l[lo], 16, 0, 0);
    }
    __syncthreads();

    short8 ah[4], al[4], bh[4], bl[4];
#pragma unroll
    for (int fI = 0; fI < 4; ++fI) {
      const int ar = wm * 64 + fI * 16 + l15;
      const int aoff = ar * 32 + ((lk * 8) ^ ((ar & 6) << 2));
      ah[fI] = *(const short8*)&As_h[aoff];
      al[fI] = *(const short8*)&As_l[aoff];
      const int br = wn * 64 + fI * 16 + l15;
      const int boff = br * 32 + ((lk * 8) ^ ((br & 6) << 2));
      bh[fI] = *(const short8*)&Bs_h[boff];
      bl[fI] = *(const short8*)&Bs_l[boff];
    }
#pragma unroll
    for (int mf = 0; mf < 4; ++mf)
#pragma unroll
      for (int nf = 0; nf < 4; ++nf) {
        acc[mf][nf] = __builtin_amdgcn_mfma_f32_16x16x32_bf16(
            ah[mf], bh[nf], acc[mf][nf], 0, 0, 0);
        acc[mf][nf] = __builtin_amdgcn_mfma_f32_16x16x32_bf16(
            ah[mf], bl[nf], acc[mf][nf], 0, 0, 0);
        acc[mf][nf] = __builtin_amdgcn_mfma_f32_16x16x32_bf16(
            al[mf], bh[nf], acc[mf][nf], 0, 0, 0);
      }
  }

#pragma unroll
  for (int mf = 0; mf < 4; ++mf)
#pragma unroll
    for (int nf = 0; nf < 4; ++nf) {
      const int col = bn + wn * 64 + nf * 16 + l15;
      const int row0 = bm + wm * 64 + mf * 16 + lk * 4;
      const float bc = bias[col];
#pragma unroll
      for (int i = 0; i < 4; ++i)
        C[(size_t)(row0 + i) * N + col] = acc[mf][nf][i] + bc;
    }
}

// ---------------------------------------------------------------------------
// qkv_prep v3 (validated R13): RMSNorm + RoPE, then PRE-SPLIT to bf16 h/l:
//   Qh/Ql [B,H,S,64] (pre-scaled by HD^-0.5), Kh/Kl [B,H,S,64],
//   Vth/Vtl [B,H,64,S] (transposed for PV's B-operand).
// ---------------------------------------------------------------------------
__global__ __launch_bounds__(256) void qkv_prep(
    const float* __restrict__ qkv, const float* __restrict__ q_scale,
    const float* __restrict__ k_scale,
    ushort* __restrict__ Qh, ushort* __restrict__ Ql,
    ushort* __restrict__ Kh, ushort* __restrict__ Kl,
    ushort* __restrict__ Vth, ushort* __restrict__ Vtl) {
  __shared__ float Vtile[64][68];
  const int lane = threadIdx.x & 63;
  const int w = threadIdx.x >> 6;
  const int st = blockIdx.x;   // s-tile of 64
  const int h = blockIdx.y;
  const int b = blockIdx.z;

  const float qs = q_scale[lane];
  const float ks = k_scale[lane];
  const int j = lane & 31;
  const float inv = powf(10000.0f, -(float)j * (1.0f / 32.0f));
  const float sgn = (lane < 32) ? -1.f : 1.f;

  for (int it = 0; it < 16; ++it) {
    const int sl = w * 16 + it;
    const int s = st * 64 + sl;
    const size_t row =
        ((size_t)(b * CS + s)) * (3 * CDM) + (size_t)h * CHD + lane;
    float qv = qkv[row];
    float kv = qkv[row + CDM];
    const float vv = qkv[row + 2 * CDM];

    float sq = qv * qv, sk2 = kv * kv;
#pragma unroll
    for (int off = 32; off > 0; off >>= 1) {
      sq += __shfl_xor(sq, off);
      sk2 += __shfl_xor(sk2, off);
    }
    qv *= rsqrtf(sq * (1.f / CHD) + 1e-6f) * qs;
    kv *= rsqrtf(sk2 * (1.f / CHD) + 1e-6f) * ks;

    const float ang = (float)s * inv;
    const float cs = cosf(ang);
    const float sn = sinf(ang);
    const float qp = __shfl_xor(qv, 32);
    const float kp = __shfl_xor(kv, 32);
    const float qr = fmaf(qv, cs, sgn * qp * sn) * 0.125f;  // pre-scale Q
    const float kr = fmaf(kv, cs, sgn * kp * sn);

    const size_t ob = (((size_t)(b * CH + h)) * CS + s) * CHD + lane;
    const ushort qhh = f32_bf16_rne(qr);
    Qh[ob] = qhh;
    Ql[ob] = f32_bf16_rne(qr - bf16_f32(qhh));
    const ushort khh = f32_bf16_rne(kr);
    Kh[ob] = khh;
    Kl[ob] = f32_bf16_rne(kr - bf16_f32(khh));
    Vtile[lane][sl] = vv;
  }
  __syncthreads();
  // write Vt[b,h,d, st*64 .. +63] split h/l, coalesced
  const int d = threadIdx.x >> 2;
  const int sq4 = (threadIdx.x & 3) * 16;
  const size_t vb = (((size_t)(b * CH + h)) * CHD + d) * CS + st * 64 + sq4;
#pragma unroll
  for (int j0 = 0; j0 < 16; j0 += 8) {
    float v8[8];
#pragma unroll
    for (int jj = 0; jj < 8; ++jj) v8[jj] = Vtile[d][sq4 + j0 + jj];
    short8 H, L;
    split8(v8, H, L);
    *(short8*)&Vth[vb + j0] = H;
    *(short8*)&Vtl[vb + j0] = L;
  }
}

// ---------------------------------------------------------------------------
// attn_fwd_mfma (validated R12/R13): swapped QK^T, XOR-swizzled LDS, 3-term
// split, balanced frame pairing, pre-split O output. 64 KB LDS -> 2 blk/CU.
// ---------------------------------------------------------------------------
__global__ __launch_bounds__(256, 2) void attn_fwd_mfma(
    const ushort* __restrict__ Qh, const ushort* __restrict__ Ql,
    const ushort* __restrict__ Kh, const ushort* __restrict__ Kl,
    const ushort* __restrict__ Vth, const ushort* __restrict__ Vtl,
    ushort* __restrict__ Oh, ushort* __restrict__ Ol) {
  __shared__ ushort Ks_h[64 * 64], Ks_l[64 * 64];   // K chunk [key][d]
  __shared__ ushort Vs_h[64 * 64], Vs_l[64 * 64];   // V^T chunk [d][key]
  __shared__ ushort Ps_h[128 * 64], Ps_l[128 * 64]; // P [q][key], wave-priv
  const int tid = threadIdx.x;
  const int b = blockIdx.x;
  const int h = blockIdx.y;
  const int fsel = blockIdx.z;
  const int f = (fsel < 8) ? (15 - fsel) : (fsel - 8);  // balanced pairing
  const int lane = tid & 63;
  const int wid = tid >> 6;
  const int l15 = lane & 15;
  const int lk = lane >> 4;
  const int qb = wid * 32;
  const size_t hb = ((size_t)(b * CH + h)) * CS * CHD;
  const size_t vtb = ((size_t)(b * CH + h)) * CHD * CS;

  short8 qh[2][2], ql[2][2];
#pragma unroll
  for (int nf = 0; nf < 2; ++nf)
#pragma unroll
    for (int ks = 0; ks < 2; ++ks) {
      const size_t qoff = hb +
          (size_t)(f * CTPF + qb + nf * 16 + l15) * CHD + ks * 32 + lk * 8;
      qh[nf][ks] = *(const short8*)(Qh + qoff);
      ql[nf][ks] = *(const short8*)(Ql + qoff);
    }

  f32x4 accO[2][4];
#pragma unroll
  for (int mo = 0; mo < 2; ++mo)
#pragma unroll
    for (int no = 0; no < 4; ++no) accO[mo][no] = (f32x4){0.f, 0.f, 0.f, 0.f};
  float m[2] = {-1e30f, -1e30f};
  float lsum[2] = {0.f, 0.f};

  const int kf0 = (f == CNF - 1) ? 1 : 0;  // last-frame quirk
  for (int kf = kf0; kf <= f; ++kf) {
#pragma unroll 1
    for (int half = 0; half < 2; ++half) {
      const int cb = kf * CTPF + half * 64;
      __syncthreads();
      {
        const int r = tid >> 2;
        const int cq = (tid & 3) * 16;
        const int mk = (r & 7) << 3;
        const size_t ko = hb + (size_t)(cb + r) * CHD + cq;
        *(short8*)&Ks_h[r * 64 + (cq ^ mk)] = *(const short8*)(Kh + ko);
        *(short8*)&Ks_h[r * 64 + ((cq + 8) ^ mk)] = *(const short8*)(Kh + ko + 8);
        *(short8*)&Ks_l[r * 64 + (cq ^ mk)] = *(const short8*)(Kl + ko);
        *(short8*)&Ks_l[r * 64 + ((cq + 8) ^ mk)] = *(const short8*)(Kl + ko + 8);
        const size_t vo = vtb + (size_t)r * CS + cb + cq;
        *(short8*)&Vs_h[r * 64 + (cq ^ mk)] = *(const short8*)(Vth + vo);
        *(short8*)&Vs_h[r * 64 + ((cq + 8) ^ mk)] = *(const short8*)(Vth + vo + 8);
        *(short8*)&Vs_l[r * 64 + (cq ^ mk)] = *(const short8*)(Vtl + vo);
        *(short8*)&Vs_l[r * 64 + ((cq + 8) ^ mk)] = *(const short8*)(Vtl + vo + 8);
      }
      __syncthreads();

      f32x4 sacc[4][2];
#pragma unroll
      for (int mf = 0; mf < 4; ++mf)
#pragma unroll
        for (int nf = 0; nf < 2; ++nf) sacc[mf][nf] = (f32x4){0.f, 0.f, 0.f, 0.f};
#pragma unroll
      for (int ks = 0; ks < 2; ++ks) {
        short8 kh[4], kl[4];
#pragma unroll
        for (int mf = 0; mf < 4; ++mf) {
          const int krow = mf * 16 + l15;
          const int base = krow * 64 + ((ks * 32 + lk * 8) ^ ((krow & 7) << 3));
          kh[mf] = *(const short8*)&Ks_h[base];
          kl[mf] = *(const short8*)&Ks_l[base];
        }
#pragma unroll
        for (int mf = 0; mf < 4; ++mf)
#pragma unroll
          for (int nf = 0; nf < 2; ++nf) {
            sacc[mf][nf] = __builtin_amdgcn_mfma_f32_16x16x32_bf16(
                kh[mf], qh[nf][ks], sacc[mf][nf], 0, 0, 0);
            sacc[mf][nf] = __builtin_amdgcn_mfma_f32_16x16x32_bf16(
                kh[mf], ql[nf][ks], sacc[mf][nf], 0, 0, 0);
            sacc[mf][nf] = __builtin_amdgcn_mfma_f32_16x16x32_bf16(
                kl[mf], qh[nf][ks], sacc[mf][nf], 0, 0, 0);
          }
      }

      float c[2];
#pragma unroll
      for (int nf = 0; nf < 2; ++nf) {
        float cm = sacc[0][nf][0];
#pragma unroll
        for (int mf = 0; mf < 4; ++mf)
#pragma unroll
          for (int i = 0; i < 4; ++i) cm = fmaxf(cm, sacc[mf][nf][i]);
        cm = fmaxf(cm, __shfl_xor(cm, 16));
        cm = fmaxf(cm, __shfl_xor(cm, 32));
        const float mn = fmaxf(m[nf], cm);
        c[nf] = __expf(m[nf] - mn);
        m[nf] = mn;
        float ps = 0.f;
        const int qrow = qb + nf * 16 + l15;
        const int qmk = (qrow & 7) << 3;
#pragma unroll
        for (int mf = 0; mf < 4; ++mf) {
          float p0 = __expf(sacc[mf][nf][0] - mn);
          float p1 = __expf(sacc[mf][nf][1] - mn);
          float p2 = __expf(sacc[mf][nf][2] - mn);
          float p3 = __expf(sacc[mf][nf][3] - mn);
          ps += (p0 + p1) + (p2 + p3);
          const ushort h0 = f32_bf16_rne(p0), h1 = f32_bf16_rne(p1);
          const ushort h2 = f32_bf16_rne(p2), h3 = f32_bf16_rne(p3);
          uint2 hw, lw;
          hw.x = (uint32_t)h0 | ((uint32_t)h1 << 16);
          hw.y = (uint32_t)h2 | ((uint32_t)h3 << 16);
          lw.x = (uint32_t)f32_bf16_rne(p0 - bf16_f32(h0)) |
                 ((uint32_t)f32_bf16_rne(p1 - bf16_f32(h1)) << 16);
          lw.y = (uint32_t)f32_bf16_rne(p2 - bf16_f32(h2)) |
                 ((uint32_t)f32_bf16_rne(p3 - bf16_f32(h3)) << 16);
          const int off = qrow * 64 + ((mf * 16 + lk * 4) ^ qmk);
          *(uint2*)&Ps_h[off] = hw;
          *(uint2*)&Ps_l[off] = lw;
        }
        ps += __shfl_xor(ps, 16);
        ps += __shfl_xor(ps, 32);
        lsum[nf] = lsum[nf] * c[nf] + ps;
      }
#pragma unroll
      for (int mo = 0; mo < 2; ++mo)
#pragma unroll
        for (int i = 0; i < 4; ++i) {
          const float cq = __shfl(c[mo], lk * 4 + i);
#pragma unroll
          for (int no = 0; no < 4; ++no) accO[mo][no][i] *= cq;
        }

#pragma unroll
      for (int ks = 0; ks < 2; ++ks) {
        short8 pa_h[2], pa_l[2], vb_h[4], vb_l[4];
#pragma unroll
        for (int mo = 0; mo < 2; ++mo) {
          const int qrow = qb + mo * 16 + l15;
          const int base = qrow * 64 + ((ks * 32 + lk * 8) ^ ((qrow & 7) << 3));
          pa_h[mo] = *(const short8*)&Ps_h[base];
          pa_l[mo] = *(const short8*)&Ps_l[base];
        }
#pragma unroll
        for (int no = 0; no < 4; ++no) {
          const int vrow = no * 16 + l15;
          const int base = vrow * 64 + ((ks * 32 + lk * 8) ^ ((vrow & 7) << 3));
          vb_h[no] = *(const short8*)&Vs_h[base];
          vb_l[no] = *(const short8*)&Vs_l[base];
        }
#pragma unroll
        for (int mo = 0; mo < 2; ++mo)
#pragma unroll
          for (int no = 0; no < 4; ++no) {
            accO[mo][no] = __builtin_amdgcn_mfma_f32_16x16x32_bf16(
                pa_h[mo], vb_h[no], accO[mo][no], 0, 0, 0);
            accO[mo][no] = __builtin_amdgcn_mfma_f32_16x16x32_bf16(
                pa_h[mo], vb_l[no], accO[mo][no], 0, 0, 0);
            accO[mo][no] = __builtin_amdgcn_mfma_f32_16x16x32_bf16(
                pa_l[mo], vb_h[no], accO[mo][no], 0, 0, 0);
          }
      }
    }
  }

  const float il0 = 1.f / lsum[0];
  const float il1 = 1.f / lsum[1];
#pragma unroll
  for (int mo = 0; mo < 2; ++mo) {
    const float myil = (mo == 0) ? il0 : il1;
#pragma unroll
    for (int i = 0; i < 4; ++i) {
      const float wv = __shfl(myil, lk * 4 + i);
      const int srow = f * CTPF + qb + mo * 16 + lk * 4 + i;
      const size_t obase = (size_t)(b * CS + srow) * CDM + h * CHD;
#pragma unroll
      for (int no = 0; no < 4; ++no) {
        const float val = accO[mo][no][i] * wv;
        const ushort hh = f32_bf16_rne(val);
        Oh[obase + no * 16 + l15] = hh;
        Ol[obase + no * 16 + l15] = f32_bf16_rne(val - bf16_f32(hh));
      }
    }
  }
}

// ---------------------------------------------------------------------------
extern "C" void kernel_launch(void* const* d_in, const int* in_sizes, int n_in,
                              void* d_out, int out_size, void* d_ws, size_t ws_size,
                              hipStream_t stream) {
  const float* x       = (const float*)d_in[0];
  const float* Wqkv    = (const float*)d_in[1];
  const float* bqkv    = (const float*)d_in[2];
  const float* q_scale = (const float*)d_in[3];
  const float* k_scale = (const float*)d_in[4];
  const float* Wout    = (const float*)d_in[5];
  const float* bout    = (const float*)d_in[6];
  float* out = (float*)d_out;

  // Workspace layout (ushort units). Temporal aliasing (validated R11-R13):
  //  region0 (50.3 MB): qkv fp32 [live GEMM1..prep]  ->  Oh/Ol [attn..GEMM2]
  //  region1 (50.3 MB): xh/xl/Wqh/Wql [split..GEMM1] -> Qh..Vtl [prep..attn]
  //  region2 ( 4.2 MB): Wouth/Woutl [split..GEMM2]
  ushort* W = (ushort*)d_ws;
  const size_t qkvN = (size_t)(CB * CS) * (3 * CDM);   // 12.58M floats
  const size_t perA = (size_t)CB * CH * CS * CHD;      // 4.19M elems
  const size_t WqN  = (size_t)(3 * CDM) * CDM;         // 3.15M
  const size_t WoN  = (size_t)CDM * CDM;               // 1.05M

  float*  qkvF = (float*)W;
  ushort* Oh   = W;                    // aliases qkvF (dead after prep)
  ushort* Ol   = W + perA;
  ushort* R1   = W + 2 * qkvN;
  ushort* Qh = R1;            ushort* Ql = R1 + perA;
  ushort* Kh = R1 + 2 * perA; ushort* Kl = R1 + 3 * perA;
  ushort* Vth = R1 + 4 * perA; ushort* Vtl = R1 + 5 * perA;
  ushort* xh  = R1;            ushort* xl  = R1 + perA;   // alias Qh/Ql
  ushort* Wqh = R1 + 2 * perA; ushort* Wql = Wqh + WqN;   // alias Kh..
  ushort* Wouth = R1 + 6 * perA; ushort* Woutl = Wouth + WoN;

  // 0) one-time fp32 -> bf16 h/l splits, single merged launch
  split3<<<2048, 256, 0, stream>>>(x, xh, xl, (int)(perA / 8),
                                   Wqkv, Wqh, Wql, (int)(WqN / 8),
                                   Wout, Wouth, Woutl, (int)(WoN / 8));

  // 1) qkv = x @ Wqkv^T + bqkv
  dim3 g1((3 * CDM) / 128, (CB * CS) / 128);
  gemm_ps<<<g1, 256, 0, stream>>>(xh, xl, Wqh, Wql, bqkv, qkvF,
                                  CB * CS, 3 * CDM, CDM);

  // 2) RMSNorm + RoPE; pre-split Q (scaled), K, Vt to bf16 h/l
  dim3 g2(CS / 64, CH, CB);
  qkv_prep<<<g2, 256, 0, stream>>>(qkvF, q_scale, k_scale,
                                   Qh, Ql, Kh, Kl, Vth, Vtl);

  // 3) frame-block-causal attention on MFMA -> pre-split O
  //    grid (batch, head, fsel): balanced complementary frame pairs per CU
  dim3 g3(CB, CH, CNF);
  attn_fwd_mfma<<<g3, 256, 0, stream>>>(Qh, Ql, Kh, Kl, Vth, Vtl, Oh, Ol);

  // 4) out = O @ Wout^T + bout
  dim3 g4(CDM / 128, (CB * CS) / 128);
  gemm_ps<<<g4, 256, 0, stream>>>(Oh, Ol, Wouth, Woutl, bout, out,
                                  CB * CS, CDM, CDM);
}